// Round 1
// baseline (1591.624 us; speedup 1.0000x reference)
//
#include <hip/hip_runtime.h>

#define NN 100000   // nodes
#define NF 128      // input features
#define D  64       // hidden dim
#define NE 1600000  // edges
#define NZ 1000000  // hypergraph incidences
#define NH 50000    // hyperedges

static __device__ __forceinline__ float waveReduceSum(float v) {
#pragma unroll
  for (int off = 32; off > 0; off >>= 1) v += __shfl_down(v, off);
  return v;
}

// ---------------------------------------------------------------------------
// Small precomputed vectors:
// sv[0:64)   u    = conv2_W @ v1          (v1 = lp_W[:64] @ head_W)
// sv[64:128) w2v  = cls_W  @ v2           (v2 = lp_W[64:] @ head_W)
// sv[128]    c_all= lp_b.head_W + head_b + conv2_b.v1 + cls_b.v2
// ---------------------------------------------------------------------------
__global__ void k_vecs(const float* __restrict__ conv2_W, const float* __restrict__ conv2_b,
                       const float* __restrict__ cls_W, const float* __restrict__ cls_b,
                       const float* __restrict__ lp_W, const float* __restrict__ lp_b,
                       const float* __restrict__ head_W, const float* __restrict__ head_b,
                       float* __restrict__ sv) {
  int t = threadIdx.x;  // 0..63, one wave
  __shared__ float v1[64], v2[64];
  float a1 = 0.f, a2 = 0.f;
  for (int c = 0; c < 64; ++c) {
    float hw = head_W[c];
    a1 = fmaf(lp_W[t * 64 + c], hw, a1);
    a2 = fmaf(lp_W[(64 + t) * 64 + c], hw, a2);
  }
  v1[t] = a1;
  v2[t] = a2;
  __syncthreads();
  float u = 0.f, w = 0.f;
  for (int c = 0; c < 64; ++c) {
    u = fmaf(conv2_W[t * 64 + c], v1[c], u);
    w = fmaf(cls_W[t * 64 + c], v2[c], w);
  }
  sv[t] = u;
  sv[64 + t] = w;
  float part = lp_b[t] * head_W[t] + conv2_b[t] * v1[t] + cls_b[t] * v2[t];
  part = waveReduceSum(part);
  if (t == 0) sv[128] = part + head_b[0];
}

// ---------------------------------------------------------------------------
// Generic tall-skinny GEMM: out[r,c] = act(in[r,:K] @ W[K,64] + b[c])
// One wave per row. W column for this lane held in registers; x row values
// broadcast via __shfl (compile-time lane -> v_readlane).
// ---------------------------------------------------------------------------
template <int K, bool BIAS, bool RELU>
__global__ __launch_bounds__(256) void k_gemm(const float* __restrict__ in,
                                              const float* __restrict__ W,
                                              const float* __restrict__ bias,
                                              float* __restrict__ out, int nrows) {
  int lane = threadIdx.x & 63;
  int wave = threadIdx.x >> 6;
  float w[K];
#pragma unroll
  for (int k = 0; k < K; ++k) w[k] = W[k * 64 + lane];
  float b = BIAS ? bias[lane] : 0.0f;
  int wid = blockIdx.x * 4 + wave;
  int nw = gridDim.x * 4;
  for (int row = wid; row < nrows; row += nw) {
    float acc0 = b, acc1 = 0.f;
    if constexpr (K == 128) {
      float v0 = in[(size_t)row * 128 + lane];
      float v1 = in[(size_t)row * 128 + 64 + lane];
#pragma unroll
      for (int k = 0; k < 64; k += 2) {
        acc0 = fmaf(__shfl(v0, k), w[k], acc0);
        acc1 = fmaf(__shfl(v0, k + 1), w[k + 1], acc1);
      }
#pragma unroll
      for (int k = 0; k < 64; k += 2) {
        acc0 = fmaf(__shfl(v1, k), w[64 + k], acc0);
        acc1 = fmaf(__shfl(v1, k + 1), w[64 + k + 1], acc1);
      }
    } else {
      float v0 = in[(size_t)row * 64 + lane];
#pragma unroll
      for (int k = 0; k < 64; k += 2) {
        acc0 = fmaf(__shfl(v0, k), w[k], acc0);
        acc1 = fmaf(__shfl(v0, k + 1), w[k + 1], acc1);
      }
    }
    float r = acc0 + acc1;
    if (RELU) r = fmaxf(r, 0.0f);
    out[(size_t)row * 64 + lane] = r;
  }
}

// ---------------------------------------------------------------------------
__global__ void k_deg(const int* __restrict__ dst, int* __restrict__ deg) {
  int e = blockIdx.x * 256 + threadIdx.x;
  if (e < NE) atomicAdd(&deg[dst[e]], 1);
}

__global__ void k_dinv(const int* __restrict__ deg, float* __restrict__ dinv) {
  int i = blockIdx.x * 256 + threadIdx.x;
  if (i < NN) dinv[i] = rsqrtf((float)(deg[i] + 1));  // +1 self-loop
}

// conv1 message scatter: acc[dst,:] += xw1[src,:] * dinv[src]*dinv[dst]
__global__ void k_gcn1_scatter(const int* __restrict__ src, const int* __restrict__ dst,
                               const float* __restrict__ dinv, const float* __restrict__ xw1,
                               float* __restrict__ acc) {
  int e = blockIdx.x * 4 + (threadIdx.x >> 6);
  if (e >= NE) return;
  int lane = threadIdx.x & 63;
  int s = src[e], d = dst[e];
  float norm = dinv[s] * dinv[d];
  atomicAdd(&acc[(size_t)d * 64 + lane], xw1[(size_t)s * 64 + lane] * norm);
}

// finalize conv1 (self loop + bias + relu) and reduce to t[i] = relu1[i].u
__global__ void k_gcn1_fin(const float* __restrict__ acc, const float* __restrict__ xw1,
                           const float* __restrict__ dinv, const float* __restrict__ conv1_b,
                           const float* __restrict__ sv, float* __restrict__ t_out) {
  int i = blockIdx.x * 4 + (threadIdx.x >> 6);
  if (i >= NN) return;
  int lane = threadIdx.x & 63;
  float di = dinv[i];
  float r = fmaxf(acc[(size_t)i * 64 + lane] + xw1[(size_t)i * 64 + lane] * (di * di) + conv1_b[lane], 0.0f);
  float p = r * sv[lane];  // u
  p = waveReduceSum(p);
  if (lane == 0) t_out[i] = p;
}

// conv2 scalarized scatter: gacc[dst] += t[src]*dinv[src]*dinv[dst]
__global__ void k_gcn2_scatter(const int* __restrict__ src, const int* __restrict__ dst,
                               const float* __restrict__ dinv, const float* __restrict__ t,
                               float* __restrict__ gacc) {
  int e = blockIdx.x * 256 + threadIdx.x;
  if (e < NE) {
    int s = src[e], d = dst[e];
    atomicAdd(&gacc[d], t[s] * dinv[s] * dinv[d]);
  }
}

// hyperedge sum scatter: xe[he,:] += C[hv,:], cnt[he]++
__global__ void k_xe_scatter(const int* __restrict__ hv, const int* __restrict__ he,
                             const float* __restrict__ C, float* __restrict__ xe,
                             int* __restrict__ cnt) {
  int n = blockIdx.x * 4 + (threadIdx.x >> 6);
  if (n >= NZ) return;
  int lane = threadIdx.x & 63;
  int v = hv[n], e = he[n];
  atomicAdd(&xe[(size_t)e * 64 + lane], C[(size_t)v * 64 + lane]);
  if (lane == 0) atomicAdd(&cnt[e], 1);
}

// Xe finalize: B[e,:] = (xe[e,:]/max(cnt,1)) @ W2[64:,:] + b2  (in place)
__global__ __launch_bounds__(256) void k_xe_fin(const float* __restrict__ W2,
                                                const float* __restrict__ b2,
                                                const int* __restrict__ cnt,
                                                float* __restrict__ xe) {
  int lane = threadIdx.x & 63;
  float w[64];
#pragma unroll
  for (int k = 0; k < 64; ++k) w[k] = W2[(64 + k) * 64 + lane];
  float b = b2[lane];
  int wid = blockIdx.x * 4 + (threadIdx.x >> 6);
  for (int e = wid; e < NH; e += gridDim.x * 4) {
    float c = (float)cnt[e];
    float m = xe[(size_t)e * 64 + lane] / fmaxf(c, 1.0f);
    float acc0 = b, acc1 = 0.f;
#pragma unroll
    for (int k = 0; k < 64; k += 2) {
      acc0 = fmaf(__shfl(m, k), w[k], acc0);
      acc1 = fmaf(__shfl(m, k + 1), w[k + 1], acc1);
    }
    xe[(size_t)e * 64 + lane] = acc0 + acc1;
  }
}

// vertex mean scatter: xv[hv,:] += relu(A[hv,:] + B[he,:]), cntv[hv]++
__global__ void k_xv_scatter(const int* __restrict__ hv, const int* __restrict__ he,
                             const float* __restrict__ A, const float* __restrict__ B,
                             float* __restrict__ xv, int* __restrict__ cntv) {
  int n = blockIdx.x * 4 + (threadIdx.x >> 6);
  if (n >= NZ) return;
  int lane = threadIdx.x & 63;
  int v = hv[n], e = he[n];
  float m = fmaxf(A[(size_t)v * 64 + lane] + B[(size_t)e * 64 + lane], 0.0f);
  atomicAdd(&xv[(size_t)v * 64 + lane], m);
  if (lane == 0) atomicAdd(&cntv[v], 1);
}

// final: hpre = 0.5*xv/max(cnt,1) + 0.5*h ; hfin = relu(hpre@Wu + bu)
// out[i] = hfin.w2v + gacc[i] + t[i]*dinv[i]^2 + c_all
__global__ __launch_bounds__(256) void k_final(const float* __restrict__ Wu, const float* __restrict__ bu,
                                               const float* __restrict__ h, const float* __restrict__ xv,
                                               const int* __restrict__ cntv, const float* __restrict__ gacc,
                                               const float* __restrict__ t, const float* __restrict__ dinv,
                                               const float* __restrict__ sv, float* __restrict__ out) {
  int lane = threadIdx.x & 63;
  float w[64];
#pragma unroll
  for (int k = 0; k < 64; ++k) w[k] = Wu[k * 64 + lane];
  float b = bu[lane];
  float w2v = sv[64 + lane];
  float c_all = sv[128];
  int wid = blockIdx.x * 4 + (threadIdx.x >> 6);
  for (int i = wid; i < NN; i += gridDim.x * 4) {
    float c = (float)cntv[i];
    float hpre = xv[(size_t)i * 64 + lane] * (0.5f / fmaxf(c, 1.0f)) + 0.5f * h[(size_t)i * 64 + lane];
    float acc0 = b, acc1 = 0.f;
#pragma unroll
    for (int k = 0; k < 64; k += 2) {
      acc0 = fmaf(__shfl(hpre, k), w[k], acc0);
      acc1 = fmaf(__shfl(hpre, k + 1), w[k + 1], acc1);
    }
    float p = fmaxf(acc0 + acc1, 0.0f) * w2v;
    p = waveReduceSum(p);
    if (lane == 0) {
      float di = dinv[i];
      out[i] = p + gacc[i] + t[i] * di * di + c_all;
    }
  }
}

// ---------------------------------------------------------------------------
extern "C" void kernel_launch(void* const* d_in, const int* in_sizes, int n_in,
                              void* d_out, int out_size, void* d_ws, size_t ws_size,
                              hipStream_t stream) {
  (void)in_sizes; (void)n_in; (void)out_size; (void)ws_size;
  const float* x       = (const float*)d_in[0];
  const int*   ei      = (const int*)d_in[1];
  const int*   hv      = (const int*)d_in[2];
  const int*   he      = (const int*)d_in[3];
  // d_in[4] = num_hyperedges scalar (known constant 50000)
  const float* conv1_W = (const float*)d_in[5];
  const float* conv1_b = (const float*)d_in[6];
  const float* conv2_W = (const float*)d_in[7];
  const float* conv2_b = (const float*)d_in[8];
  const float* lin_W   = (const float*)d_in[9];
  const float* lin_b   = (const float*)d_in[10];
  const float* W1      = (const float*)d_in[11];
  const float* b1      = (const float*)d_in[12];
  const float* W2      = (const float*)d_in[13];
  const float* b2      = (const float*)d_in[14];
  const float* Wu      = (const float*)d_in[15];
  const float* bu      = (const float*)d_in[16];
  const float* cls_W   = (const float*)d_in[17];
  const float* cls_b   = (const float*)d_in[18];
  const float* lp_W    = (const float*)d_in[19];
  const float* lp_b    = (const float*)d_in[20];
  const float* head_W  = (const float*)d_in[21];
  const float* head_b  = (const float*)d_in[22];
  const int* src = ei;
  const int* dst = ei + NE;
  float* out = (float*)d_out;

  // workspace layout (floats); aliasing: P = xw1 -> C -> Xv_sum, Q = acc1 -> A
  float* H    = (float*)d_ws;            // N*64   h (lives whole call)
  float* P    = H + (size_t)NN * 64;     // N*64
  float* Q    = P + (size_t)NN * 64;     // N*64
  float* XE   = Q + (size_t)NN * 64;     // NH*64  Xe_sum then B (in place)
  float* DINV = XE + (size_t)NH * 64;    // N
  float* T    = DINV + NN;               // N
  float* GACC = T + NN;                  // N
  float* SV   = GACC + NN;               // 192
  int* DEG    = (int*)(SV + 192);        // N
  int* CNTHE  = DEG + NN;                // NH
  int* CNTV   = CNTHE + NH;              // N
  // total ~88 MiB

  hipMemsetAsync(Q, 0, (size_t)NN * 64 * 4, stream);    // conv1 accumulator
  hipMemsetAsync(XE, 0, (size_t)NH * 64 * 4, stream);
  hipMemsetAsync(DEG, 0, (size_t)NN * 4, stream);
  hipMemsetAsync(GACC, 0, (size_t)NN * 4, stream);
  hipMemsetAsync(CNTHE, 0, (size_t)NH * 4, stream);
  hipMemsetAsync(CNTV, 0, (size_t)NN * 4, stream);

  k_vecs<<<1, 64, 0, stream>>>(conv2_W, conv2_b, cls_W, cls_b, lp_W, lp_b, head_W, head_b, SV);

  // xw1 = x @ conv1_W (bias deferred past aggregation); h = relu(x @ lin_W + lin_b)
  k_gemm<128, false, false><<<2048, 256, 0, stream>>>(x, conv1_W, nullptr, P, NN);
  k_gemm<128, true, true><<<2048, 256, 0, stream>>>(x, lin_W, lin_b, H, NN);

  k_deg<<<(NE + 255) / 256, 256, 0, stream>>>(dst, DEG);
  k_dinv<<<(NN + 255) / 256, 256, 0, stream>>>(DEG, DINV);

  k_gcn1_scatter<<<NE / 4, 256, 0, stream>>>(src, dst, DINV, P, Q);
  k_gcn1_fin<<<NN / 4, 256, 0, stream>>>(Q, P, DINV, conv1_b, SV, T);
  k_gcn2_scatter<<<(NE + 255) / 256, 256, 0, stream>>>(src, dst, DINV, T, GACC);

  // hyper branch dense parts: A = h @ W2[:64] (into Q), C = h @ W1 + b1 (into P)
  k_gemm<64, false, false><<<2048, 256, 0, stream>>>(H, W2, nullptr, Q, NN);
  k_gemm<64, true, false><<<2048, 256, 0, stream>>>(H, W1, b1, P, NN);

  k_xe_scatter<<<NZ / 4, 256, 0, stream>>>(hv, he, P, XE, CNTHE);
  k_xe_fin<<<2048, 256, 0, stream>>>(W2, b2, CNTHE, XE);

  hipMemsetAsync(P, 0, (size_t)NN * 64 * 4, stream);    // Xv accumulator (C consumed)
  k_xv_scatter<<<NZ / 4, 256, 0, stream>>>(hv, he, Q, XE, P, CNTV);

  k_final<<<2048, 256, 0, stream>>>(Wu, bu, H, P, CNTV, GACC, T, DINV, SV, out);
}

// Round 2
// 1504.596 us; speedup vs baseline: 1.0578x; 1.0578x over previous
//
#include <hip/hip_runtime.h>

#define NN 100000   // nodes
#define NF 128      // input features
#define D  64       // hidden dim
#define NE 1600000  // edges
#define NZ 1000000  // hypergraph incidences
#define NH 50000    // hyperedges

#define NS (NN + NH + NN)          // 250000 concatenated histogram entries
#define TOT (NE + 2 * NZ)          // 3600000 total adjacency entries
#define NB 245                     // scan blocks: ceil(NS/1024)

static __device__ __forceinline__ float waveReduceSum(float v) {
#pragma unroll
  for (int off = 32; off > 0; off >>= 1) v += __shfl_down(v, off);
  return v;
}

// ---------------------------------------------------------------------------
// sv[0:64)   u    = conv2_W @ v1          (v1 = lp_W[:64] @ head_W)
// sv[64:128) w2v  = cls_W  @ v2           (v2 = lp_W[64:] @ head_W)
// sv[128]    c_all= lp_b.head_W + head_b + conv2_b.v1 + cls_b.v2
// ---------------------------------------------------------------------------
__global__ void k_vecs(const float* __restrict__ conv2_W, const float* __restrict__ conv2_b,
                       const float* __restrict__ cls_W, const float* __restrict__ cls_b,
                       const float* __restrict__ lp_W, const float* __restrict__ lp_b,
                       const float* __restrict__ head_W, const float* __restrict__ head_b,
                       float* __restrict__ sv) {
  int t = threadIdx.x;  // 0..63, one wave
  __shared__ float v1[64], v2[64];
  float a1 = 0.f, a2 = 0.f;
  for (int c = 0; c < 64; ++c) {
    float hw = head_W[c];
    a1 = fmaf(lp_W[t * 64 + c], hw, a1);
    a2 = fmaf(lp_W[(64 + t) * 64 + c], hw, a2);
  }
  v1[t] = a1;
  v2[t] = a2;
  __syncthreads();
  float u = 0.f, w = 0.f;
  for (int c = 0; c < 64; ++c) {
    u = fmaf(conv2_W[t * 64 + c], v1[c], u);
    w = fmaf(cls_W[t * 64 + c], v2[c], w);
  }
  sv[t] = u;
  sv[64 + t] = w;
  float part = lp_b[t] * head_W[t] + conv2_b[t] * v1[t] + cls_b[t] * v2[t];
  part = waveReduceSum(part);
  if (t == 0) sv[128] = part + head_b[0];
}

// ---------------------------------------------------------------------------
// Tall-skinny GEMM: out[r,c] = act(in[r,:K] @ W[K,64] + b[c]); one wave/row.
// ---------------------------------------------------------------------------
template <int K, bool BIAS, bool RELU>
__global__ __launch_bounds__(256) void k_gemm(const float* __restrict__ in,
                                              const float* __restrict__ W,
                                              const float* __restrict__ bias,
                                              float* __restrict__ out, int nrows) {
  int lane = threadIdx.x & 63;
  int wave = threadIdx.x >> 6;
  float w[K];
#pragma unroll
  for (int k = 0; k < K; ++k) w[k] = W[k * 64 + lane];
  float b = BIAS ? bias[lane] : 0.0f;
  int wid = blockIdx.x * 4 + wave;
  int nw = gridDim.x * 4;
  for (int row = wid; row < nrows; row += nw) {
    float acc0 = b, acc1 = 0.f;
    if constexpr (K == 128) {
      float v0 = in[(size_t)row * 128 + lane];
      float v1 = in[(size_t)row * 128 + 64 + lane];
#pragma unroll
      for (int k = 0; k < 64; k += 2) {
        acc0 = fmaf(__shfl(v0, k), w[k], acc0);
        acc1 = fmaf(__shfl(v0, k + 1), w[k + 1], acc1);
      }
#pragma unroll
      for (int k = 0; k < 64; k += 2) {
        acc0 = fmaf(__shfl(v1, k), w[64 + k], acc0);
        acc1 = fmaf(__shfl(v1, k + 1), w[64 + k + 1], acc1);
      }
    } else {
      float v0 = in[(size_t)row * 64 + lane];
#pragma unroll
      for (int k = 0; k < 64; k += 2) {
        acc0 = fmaf(__shfl(v0, k), w[k], acc0);
        acc1 = fmaf(__shfl(v0, k + 1), w[k + 1], acc1);
      }
    }
    float r = acc0 + acc1;
    if (RELU) r = fmaxf(r, 0.0f);
    out[(size_t)row * 64 + lane] = r;
  }
}

// ---------------------------------------------------------------------------
// CSR build: concatenated histogram -> scan -> bucket
// ---------------------------------------------------------------------------
__global__ void k_count(const int* __restrict__ dst, const int* __restrict__ he,
                        const int* __restrict__ hv, int* __restrict__ cnt) {
  int e = blockIdx.x * 256 + threadIdx.x;
  if (e < NE) atomicAdd(&cnt[dst[e]], 1);
  if (e < NZ) {
    atomicAdd(&cnt[NN + he[e]], 1);
    atomicAdd(&cnt[NN + NH + hv[e]], 1);
  }
}

__global__ __launch_bounds__(256) void k_scan1(const int* __restrict__ cnt,
                                               int* __restrict__ off, int* __restrict__ bsum) {
  __shared__ int sh[256];
  int t = threadIdx.x;
  int base = blockIdx.x * 1024 + t * 4;
  int v0 = 0, v1 = 0, v2 = 0, v3 = 0;
  if (base + 0 < NS) v0 = cnt[base + 0];
  if (base + 1 < NS) v1 = cnt[base + 1];
  if (base + 2 < NS) v2 = cnt[base + 2];
  if (base + 3 < NS) v3 = cnt[base + 3];
  int s = v0 + v1 + v2 + v3;
  sh[t] = s;
  __syncthreads();
#pragma unroll
  for (int d = 1; d < 256; d <<= 1) {
    int x = (t >= d) ? sh[t - d] : 0;
    __syncthreads();
    sh[t] += x;
    __syncthreads();
  }
  if (t == 255) bsum[blockIdx.x] = sh[255];
  int run = sh[t] - s;
  if (base + 0 < NS) off[base + 0] = run;
  run += v0;
  if (base + 1 < NS) off[base + 1] = run;
  run += v1;
  if (base + 2 < NS) off[base + 2] = run;
  run += v2;
  if (base + 3 < NS) off[base + 3] = run;
}

__global__ __launch_bounds__(256) void k_scan2(int* __restrict__ bsum) {
  __shared__ int sh[256];
  int t = threadIdx.x;
  int v = (t < NB) ? bsum[t] : 0;
  sh[t] = v;
  __syncthreads();
#pragma unroll
  for (int d = 1; d < 256; d <<= 1) {
    int x = (t >= d) ? sh[t - d] : 0;
    __syncthreads();
    sh[t] += x;
    __syncthreads();
  }
  if (t < NB) bsum[t] = sh[t] - v;  // exclusive
}

__global__ void k_scan3(int* __restrict__ off, int* __restrict__ cur,
                        const int* __restrict__ bsum) {
  int i = blockIdx.x * 256 + threadIdx.x;
  if (i < NS) {
    int o = off[i] + bsum[i >> 10];
    off[i] = o;
    cur[i] = o;
  } else if (i == NS) {
    off[i] = TOT;
    cur[i] = TOT;
  }
}

__global__ void k_bucket(const int* __restrict__ src, const int* __restrict__ dst,
                         const int* __restrict__ he, const int* __restrict__ hv,
                         int* __restrict__ cur, int* __restrict__ adj) {
  int e = blockIdx.x * 256 + threadIdx.x;
  if (e < NE) {
    int d = dst[e];
    adj[atomicAdd(&cur[d], 1)] = src[e];
  }
  if (e < NZ) {
    int h = he[e], v = hv[e];
    adj[atomicAdd(&cur[NN + h], 1)] = v;
    adj[atomicAdd(&cur[NN + NH + v], 1)] = h;
  }
}

__global__ void k_dinv(const int* __restrict__ off, float* __restrict__ dinv) {
  int i = blockIdx.x * 256 + threadIdx.x;
  if (i < NN) dinv[i] = rsqrtf((float)(off[i + 1] - off[i] + 1));  // +1 self-loop
}

// ---------------------------------------------------------------------------
// conv1 gather + finalize: t[i] = relu((sum_s xw1[s]*dinv[s] + xw1[i]*di)*di + b) . u
// ---------------------------------------------------------------------------
__global__ __launch_bounds__(256) void k_gcn1_gather(const int* __restrict__ off,
                                                     const int* __restrict__ adj,
                                                     const float* __restrict__ xw1,
                                                     const float* __restrict__ dinv,
                                                     const float* __restrict__ conv1_b,
                                                     const float* __restrict__ sv,
                                                     float* __restrict__ t_out) {
  int i = blockIdx.x * 4 + (threadIdx.x >> 6);
  if (i >= NN) return;
  int lane = threadIdx.x & 63;
  int beg = off[i], end = off[i + 1];
  float acc = 0.f;
  for (int j = beg; j < end; ++j) {
    int s = adj[j];
    acc = fmaf(xw1[(size_t)s * 64 + lane], dinv[s], acc);
  }
  float di = dinv[i];
  float r = fmaxf(fmaf(fmaf(xw1[(size_t)i * 64 + lane], di, acc), di, conv1_b[lane]), 0.f);
  float p = waveReduceSum(r * sv[lane]);
  if (lane == 0) t_out[i] = p;
}

// ---------------------------------------------------------------------------
// Xe gather + matvec: B[e,:] = mean_{v in e} C[v,:] @ W2[64:,:] + b2
// ---------------------------------------------------------------------------
__global__ __launch_bounds__(256) void k_xe_gather(const int* __restrict__ off,
                                                   const int* __restrict__ adj,
                                                   const float* __restrict__ C,
                                                   const float* __restrict__ W2,
                                                   const float* __restrict__ b2,
                                                   float* __restrict__ B) {
  int lane = threadIdx.x & 63;
  float w[64];
#pragma unroll
  for (int k = 0; k < 64; ++k) w[k] = W2[(64 + k) * 64 + lane];
  float b = b2[lane];
  int wid = blockIdx.x * 4 + (threadIdx.x >> 6);
  for (int e = wid; e < NH; e += gridDim.x * 4) {
    int beg = off[NN + e], end = off[NN + e + 1];
    float acc = 0.f;
    for (int j = beg; j < end; ++j) {
      int v = adj[j];
      acc += C[(size_t)v * 64 + lane];
    }
    float m = acc / fmaxf((float)(end - beg), 1.0f);
    float a0 = b, a1 = 0.f;
#pragma unroll
    for (int k = 0; k < 64; k += 2) {
      a0 = fmaf(__shfl(m, k), w[k], a0);
      a1 = fmaf(__shfl(m, k + 1), w[k + 1], a1);
    }
    B[(size_t)e * 64 + lane] = a0 + a1;
  }
}

// ---------------------------------------------------------------------------
// Final fused kernel, one wave per node i:
//   xv   = mean_{e ni i} relu(A[i]+B[e])
//   hpre = 0.5*xv + 0.5*h[i];  hfin = relu(hpre@Wu + bu)
//   g    = sum_{s->i} t[s]*dinv[s]        (gcn2 gather, lanes stride edges)
//   out  = hfin.w2v + g*di + t[i]*di^2 + c_all
// ---------------------------------------------------------------------------
__global__ __launch_bounds__(256) void k_final(const int* __restrict__ off,
                                               const int* __restrict__ adj,
                                               const float* __restrict__ A,
                                               const float* __restrict__ B,
                                               const float* __restrict__ h,
                                               const float* __restrict__ t,
                                               const float* __restrict__ dinv,
                                               const float* __restrict__ Wu,
                                               const float* __restrict__ bu,
                                               const float* __restrict__ sv,
                                               float* __restrict__ out) {
  int lane = threadIdx.x & 63;
  float w[64];
#pragma unroll
  for (int k = 0; k < 64; ++k) w[k] = Wu[k * 64 + lane];
  float b = bu[lane];
  float w2v = sv[64 + lane];
  float c_all = sv[128];
  int wid = blockIdx.x * 4 + (threadIdx.x >> 6);
  for (int i = wid; i < NN; i += gridDim.x * 4) {
    float a = A[(size_t)i * 64 + lane];
    int beg = off[NN + NH + i], end = off[NN + NH + i + 1];
    float accm = 0.f;
    for (int j = beg; j < end; ++j) {
      int e = adj[j];
      accm += fmaxf(a + B[(size_t)e * 64 + lane], 0.f);
    }
    float hpre = accm * (0.5f / fmaxf((float)(end - beg), 1.0f)) + 0.5f * h[(size_t)i * 64 + lane];
    float a0 = b, a1 = 0.f;
#pragma unroll
    for (int k = 0; k < 64; k += 2) {
      a0 = fmaf(__shfl(hpre, k), w[k], a0);
      a1 = fmaf(__shfl(hpre, k + 1), w[k + 1], a1);
    }
    float part = fmaxf(a0 + a1, 0.f) * w2v;
    // gcn2 scalar gather over dst-CSR (section 0)
    float di = dinv[i];
    int db = off[i], de = off[i + 1];
    float g = 0.f;
    for (int j = db + lane; j < de; j += 64) {
      int s = adj[j];
      g = fmaf(t[s], dinv[s], g);
    }
    float tot = waveReduceSum(part + g * di);
    if (lane == 0) out[i] = tot + t[i] * di * di + c_all;
  }
}

// ---------------------------------------------------------------------------
extern "C" void kernel_launch(void* const* d_in, const int* in_sizes, int n_in,
                              void* d_out, int out_size, void* d_ws, size_t ws_size,
                              hipStream_t stream) {
  (void)in_sizes; (void)n_in; (void)out_size; (void)ws_size;
  const float* x       = (const float*)d_in[0];
  const int*   ei      = (const int*)d_in[1];
  const int*   hv      = (const int*)d_in[2];
  const int*   he      = (const int*)d_in[3];
  const float* conv1_W = (const float*)d_in[5];
  const float* conv1_b = (const float*)d_in[6];
  const float* conv2_W = (const float*)d_in[7];
  const float* conv2_b = (const float*)d_in[8];
  const float* lin_W   = (const float*)d_in[9];
  const float* lin_b   = (const float*)d_in[10];
  const float* W1      = (const float*)d_in[11];
  const float* b1      = (const float*)d_in[12];
  const float* W2      = (const float*)d_in[13];
  const float* b2      = (const float*)d_in[14];
  const float* Wu      = (const float*)d_in[15];
  const float* bu      = (const float*)d_in[16];
  const float* cls_W   = (const float*)d_in[17];
  const float* cls_b   = (const float*)d_in[18];
  const float* lp_W    = (const float*)d_in[19];
  const float* lp_b    = (const float*)d_in[20];
  const float* head_W  = (const float*)d_in[21];
  const float* head_b  = (const float*)d_in[22];
  const int* src = ei;
  const int* dst = ei + NE;
  float* out = (float*)d_out;

  // workspace layout (4B units). Aliasing: P = xw1 -> C.
  float* H    = (float*)d_ws;              // N*64
  float* P    = H + (size_t)NN * 64;       // N*64   xw1 then C
  float* Q    = P + (size_t)NN * 64;       // N*64   A
  float* XE   = Q + (size_t)NN * 64;       // NH*64  B
  float* DINV = XE + (size_t)NH * 64;      // N
  float* T    = DINV + NN;                 // N
  float* SV   = T + NN;                    // 192
  int* CNT    = (int*)(SV + 192);          // NS
  int* OFF    = CNT + NS;                  // NS+1
  int* CUR    = OFF + NS + 1;              // NS+1
  int* BSUM   = CUR + NS + 1;              // 256
  int* ADJ    = BSUM + 256;                // TOT (3.6M)
  // total ~108 MiB

  hipMemsetAsync(CNT, 0, (size_t)NS * 4, stream);

  k_vecs<<<1, 64, 0, stream>>>(conv2_W, conv2_b, cls_W, cls_b, lp_W, lp_b, head_W, head_b, SV);

  // CSR build
  k_count<<<(NE + 255) / 256, 256, 0, stream>>>(dst, he, hv, CNT);
  k_scan1<<<NB, 256, 0, stream>>>(CNT, OFF, BSUM);
  k_scan2<<<1, 256, 0, stream>>>(BSUM);
  k_scan3<<<(NS + 256) / 256, 256, 0, stream>>>(OFF, CUR, BSUM);
  k_dinv<<<(NN + 255) / 256, 256, 0, stream>>>(OFF, DINV);
  k_bucket<<<(NE + 255) / 256, 256, 0, stream>>>(src, dst, he, hv, CUR, ADJ);

  // dense: xw1 = x @ conv1_W (bias deferred); h = relu(x @ lin_W + lin_b)
  k_gemm<128, false, false><<<2048, 256, 0, stream>>>(x, conv1_W, nullptr, P, NN);
  k_gemm<128, true, true><<<2048, 256, 0, stream>>>(x, lin_W, lin_b, H, NN);

  // GCN branch collapsed to t[i] (conv2 folded into k_final)
  k_gcn1_gather<<<NN / 4, 256, 0, stream>>>(OFF, ADJ, P, DINV, conv1_b, SV, T);

  // hyper branch dense parts: A = h @ W2[:64] (Q), C = h @ W1 + b1 (P, xw1 dead)
  k_gemm<64, false, false><<<2048, 256, 0, stream>>>(H, W2, nullptr, Q, NN);
  k_gemm<64, true, false><<<2048, 256, 0, stream>>>(H, W1, b1, P, NN);

  k_xe_gather<<<2048, 256, 0, stream>>>(OFF, ADJ, P, W2, b2, XE);

  k_final<<<2048, 256, 0, stream>>>(OFF, ADJ, Q, XE, H, T, DINV, Wu, bu, SV, out);
}

// Round 3
// 945.841 us; speedup vs baseline: 1.6828x; 1.5907x over previous
//
#include <hip/hip_runtime.h>

#define NN 100000   // nodes
#define NF 128      // input features
#define D  64       // hidden dim
#define NE 1600000  // edges
#define NZ 1000000  // hypergraph incidences
#define NH 50000    // hyperedges

#define NS (NN + NH + NN)          // 250000 concatenated id space
#define TOT (NE + 2 * NZ)          // 3600000 adjacency entries
#define NBUK 977                   // ceil(NS/256) buckets of 256 ids
#define NWG1 256                   // phase-1 workgroups
#define P2CAP 6144                 // max entries per bucket (mean 4096-5120, 14 sigma)

static __device__ __forceinline__ float waveReduceSum(float v) {
#pragma unroll
  for (int off = 32; off > 0; off >>= 1) v += __shfl_down(v, off);
  return v;
}

// ---------------------------------------------------------------------------
// sv[0:64)   u    = conv2_W @ v1          (v1 = lp_W[:64] @ head_W)
// sv[64:128) w2v  = cls_W  @ v2           (v2 = lp_W[64:] @ head_W)
// sv[128]    c_all= lp_b.head_W + head_b + conv2_b.v1 + cls_b.v2
// ---------------------------------------------------------------------------
__global__ void k_vecs(const float* __restrict__ conv2_W, const float* __restrict__ conv2_b,
                       const float* __restrict__ cls_W, const float* __restrict__ cls_b,
                       const float* __restrict__ lp_W, const float* __restrict__ lp_b,
                       const float* __restrict__ head_W, const float* __restrict__ head_b,
                       float* __restrict__ sv) {
  int t = threadIdx.x;  // 0..63, one wave
  __shared__ float v1[64], v2[64];
  float a1 = 0.f, a2 = 0.f;
  for (int c = 0; c < 64; ++c) {
    float hw = head_W[c];
    a1 = fmaf(lp_W[t * 64 + c], hw, a1);
    a2 = fmaf(lp_W[(64 + t) * 64 + c], hw, a2);
  }
  v1[t] = a1;
  v2[t] = a2;
  __syncthreads();
  float u = 0.f, w = 0.f;
  for (int c = 0; c < 64; ++c) {
    u = fmaf(conv2_W[t * 64 + c], v1[c], u);
    w = fmaf(cls_W[t * 64 + c], v2[c], w);
  }
  sv[t] = u;
  sv[64 + t] = w;
  float part = lp_b[t] * head_W[t] + conv2_b[t] * v1[t] + cls_b[t] * v2[t];
  part = waveReduceSum(part);
  if (t == 0) sv[128] = part + head_b[0];
}

// ---------------------------------------------------------------------------
// Tall-skinny GEMM: out[r,c] = scale?*(act(in[r,:K] @ W[K,64] + b[c]))
// ---------------------------------------------------------------------------
template <int K, bool BIAS, bool RELU, bool SCALE>
__global__ __launch_bounds__(256) void k_gemm(const float* __restrict__ in,
                                              const float* __restrict__ W,
                                              const float* __restrict__ bias,
                                              const float* __restrict__ scale,
                                              float* __restrict__ out, int nrows) {
  int lane = threadIdx.x & 63;
  int wave = threadIdx.x >> 6;
  float w[K];
#pragma unroll
  for (int k = 0; k < K; ++k) w[k] = W[k * 64 + lane];
  float b = BIAS ? bias[lane] : 0.0f;
  int wid = blockIdx.x * 4 + wave;
  int nw = gridDim.x * 4;
  for (int row = wid; row < nrows; row += nw) {
    float acc0 = b, acc1 = 0.f;
    if constexpr (K == 128) {
      float v0 = in[(size_t)row * 128 + lane];
      float v1 = in[(size_t)row * 128 + 64 + lane];
#pragma unroll
      for (int k = 0; k < 64; k += 2) {
        acc0 = fmaf(__shfl(v0, k), w[k], acc0);
        acc1 = fmaf(__shfl(v0, k + 1), w[k + 1], acc1);
      }
#pragma unroll
      for (int k = 0; k < 64; k += 2) {
        acc0 = fmaf(__shfl(v1, k), w[64 + k], acc0);
        acc1 = fmaf(__shfl(v1, k + 1), w[64 + k + 1], acc1);
      }
    } else {
      float v0 = in[(size_t)row * 64 + lane];
#pragma unroll
      for (int k = 0; k < 64; k += 2) {
        acc0 = fmaf(__shfl(v0, k), w[k], acc0);
        acc1 = fmaf(__shfl(v0, k + 1), w[k + 1], acc1);
      }
    }
    float r = acc0 + acc1;
    if (RELU) r = fmaxf(r, 0.0f);
    if (SCALE) r *= scale[row];
    out[(size_t)row * 64 + lane] = r;
  }
}

// ---------------------------------------------------------------------------
// CSR build: LDS-binned counting sort.
// item j: j<NE -> (id=dst, val=src); j<NE+NZ -> (id=NN+he, val=hv);
//         else -> (id=NN+NH+hv, val=he)
// ---------------------------------------------------------------------------
__global__ __launch_bounds__(256) void k_ccount(const int* __restrict__ dst,
                                                const int* __restrict__ he,
                                                const int* __restrict__ hv,
                                                int* __restrict__ gcnt) {
  __shared__ int hist[NBUK];
  for (int b = threadIdx.x; b < NBUK; b += 256) hist[b] = 0;
  __syncthreads();
  int step = gridDim.x * 256;
  for (int j = blockIdx.x * 256 + threadIdx.x; j < TOT; j += step) {
    int id;
    if (j < NE) id = dst[j];
    else if (j < NE + NZ) id = NN + he[j - NE];
    else id = NN + NH + hv[j - NE - NZ];
    atomicAdd(&hist[id >> 8], 1);
  }
  __syncthreads();
  for (int b = threadIdx.x; b < NBUK; b += 256) {
    int c = hist[b];
    if (c) atomicAdd(&gcnt[b], c);
  }
}

__global__ __launch_bounds__(1024) void k_cscan(const int* __restrict__ gcnt,
                                                int* __restrict__ gbase,
                                                int* __restrict__ gcur) {
  __shared__ int sh[1024];
  int t = threadIdx.x;
  int v = (t < NBUK) ? gcnt[t] : 0;
  sh[t] = v;
  __syncthreads();
#pragma unroll
  for (int d = 1; d < 1024; d <<= 1) {
    int x = (t >= d) ? sh[t - d] : 0;
    __syncthreads();
    sh[t] += x;
    __syncthreads();
  }
  int excl = sh[t] - v;
  if (t < NBUK) {
    gbase[t] = excl;
    gcur[t] = excl;
  }
  if (t == 1023) gbase[NBUK] = sh[1023];
}

__global__ __launch_bounds__(1024) void k_phase1(const int* __restrict__ src,
                                                 const int* __restrict__ dst,
                                                 const int* __restrict__ he,
                                                 const int* __restrict__ hv,
                                                 int* __restrict__ gcur,
                                                 int* __restrict__ adj) {
  __shared__ int cnt[NBUK], base[NBUK], cur[NBUK];
  int tid = threadIdx.x;
  for (int b = tid; b < NBUK; b += 1024) { cnt[b] = 0; cur[b] = 0; }
  __syncthreads();
  int per = (TOT + NWG1 - 1) / NWG1;
  int s0 = blockIdx.x * per;
  int s1 = s0 + per; if (s1 > TOT) s1 = TOT;
  for (int j = s0 + tid; j < s1; j += 1024) {
    int id;
    if (j < NE) id = dst[j];
    else if (j < NE + NZ) id = NN + he[j - NE];
    else id = NN + NH + hv[j - NE - NZ];
    atomicAdd(&cnt[id >> 8], 1);
  }
  __syncthreads();
  for (int b = tid; b < NBUK; b += 1024) {
    int c = cnt[b];
    if (c) base[b] = atomicAdd(&gcur[b], c);
  }
  __syncthreads();
  for (int j = s0 + tid; j < s1; j += 1024) {
    int id, val;
    if (j < NE)           { id = dst[j];                val = src[j]; }
    else if (j < NE + NZ) { id = NN + he[j - NE];       val = hv[j - NE]; }
    else                  { id = NN + NH + hv[j - NE - NZ]; val = he[j - NE - NZ]; }
    int b = id >> 8;
    int slot = base[b] + atomicAdd(&cur[b], 1);
    adj[slot] = ((id & 255) << 17) | val;   // val < 131072
  }
}

__global__ __launch_bounds__(256) void k_phase2(const int* __restrict__ gbase,
                                                int* __restrict__ adj,
                                                int* __restrict__ off) {
  __shared__ int ent[P2CAP];
  __shared__ int hist[256];
  int b = blockIdx.x, tid = threadIdx.x;
  int s = gbase[b];
  int n = gbase[b + 1] - s;
  if (n > P2CAP) n = P2CAP;  // safety; cannot trigger on this dataset
  hist[tid] = 0;
  __syncthreads();
  for (int k = tid; k < n; k += 256) {
    int v = adj[s + k];
    ent[k] = v;
    atomicAdd(&hist[v >> 17], 1);
  }
  __syncthreads();
  int c = hist[tid];
#pragma unroll
  for (int d = 1; d < 256; d <<= 1) {
    int x = (tid >= d) ? hist[tid - d] : 0;
    __syncthreads();
    hist[tid] += x;
    __syncthreads();
  }
  int excl = hist[tid] - c;
  hist[tid] = excl;           // only own slot touched; no race
  int gid = (b << 8) + tid;
  if (gid <= NS) off[gid] = s + excl;
  __syncthreads();
  for (int k = tid; k < n; k += 256) {
    int v = ent[k];
    int pos = atomicAdd(&hist[v >> 17], 1);
    adj[s + pos] = v & 0x1FFFF;
  }
}

__global__ void k_dinv(const int* __restrict__ off, float* __restrict__ dinv) {
  int i = blockIdx.x * 256 + threadIdx.x;
  if (i < NN) dinv[i] = rsqrtf((float)(off[i + 1] - off[i] + 1));  // +1 self-loop
}

// ---------------------------------------------------------------------------
// conv1 gather (xw1p pre-scaled by dinv[row]):
//   t'[i] = dinv[i] * ( relu( dinv[i]*(sum_s xw1p[s] + xw1p[i]) + conv1_b ) . u )
// ---------------------------------------------------------------------------
__global__ __launch_bounds__(256) void k_gcn1_gather(const int* __restrict__ off,
                                                     const int* __restrict__ adj,
                                                     const float* __restrict__ xw1p,
                                                     const float* __restrict__ dinv,
                                                     const float* __restrict__ conv1_b,
                                                     const float* __restrict__ sv,
                                                     float* __restrict__ tp) {
  int i = blockIdx.x * 4 + (threadIdx.x >> 6);
  if (i >= NN) return;
  int lane = threadIdx.x & 63;
  int beg = off[i], end = off[i + 1];
  float acc = 0.f;
  for (int j0 = beg; j0 < end; j0 += 64) {
    int m = end - j0; if (m > 64) m = 64;
    int a = (lane < m) ? adj[j0 + lane] : 0;
    for (int k = 0; k < m; ++k) {
      int s = __shfl(a, k);
      acc += xw1p[(size_t)s * 64 + lane];
    }
  }
  float di = dinv[i];
  float r = fmaxf(fmaf(acc + xw1p[(size_t)i * 64 + lane], di, conv1_b[lane]), 0.f);
  float p = waveReduceSum(r * sv[lane]);
  if (lane == 0) tp[i] = p * di;
}

// ---------------------------------------------------------------------------
// Xe gather + matvec: B[e,:] = (mean_{v in e} C[v,:]) @ W2[64:,:] + b2
// ---------------------------------------------------------------------------
__global__ __launch_bounds__(256) void k_xe_gather(const int* __restrict__ off,
                                                   const int* __restrict__ adj,
                                                   const float* __restrict__ C,
                                                   const float* __restrict__ W2,
                                                   const float* __restrict__ b2,
                                                   float* __restrict__ B) {
  int lane = threadIdx.x & 63;
  float w[64];
#pragma unroll
  for (int k = 0; k < 64; ++k) w[k] = W2[(64 + k) * 64 + lane];
  float b = b2[lane];
  int wid = blockIdx.x * 4 + (threadIdx.x >> 6);
  for (int e = wid; e < NH; e += gridDim.x * 4) {
    int beg = off[NN + e], end = off[NN + e + 1];
    float acc = 0.f;
    for (int j0 = beg; j0 < end; j0 += 64) {
      int m = end - j0; if (m > 64) m = 64;
      int a = (lane < m) ? adj[j0 + lane] : 0;
      for (int k = 0; k < m; ++k) {
        int v = __shfl(a, k);
        acc += C[(size_t)v * 64 + lane];
      }
    }
    float mm = acc / fmaxf((float)(end - beg), 1.0f);
    float a0 = b, a1 = 0.f;
#pragma unroll
    for (int k = 0; k < 64; k += 2) {
      a0 = fmaf(__shfl(mm, k), w[k], a0);
      a1 = fmaf(__shfl(mm, k + 1), w[k + 1], a1);
    }
    B[(size_t)e * 64 + lane] = a0 + a1;
  }
}

// ---------------------------------------------------------------------------
// Final fused kernel, one wave per node i:
//   xv   = mean_{e ni i} relu(A[i]+B[e]);  hfin = relu((0.5*xv+0.5*h[i])@Wu+bu)
//   g    = sum_{s->i} t'[s]  (gcn2 gather)
//   out  = hfin.w2v + dinv[i]*(g + t'[i]) + c_all
// ---------------------------------------------------------------------------
__global__ __launch_bounds__(256) void k_final(const int* __restrict__ off,
                                               const int* __restrict__ adj,
                                               const float* __restrict__ A,
                                               const float* __restrict__ B,
                                               const float* __restrict__ h,
                                               const float* __restrict__ tp,
                                               const float* __restrict__ dinv,
                                               const float* __restrict__ Wu,
                                               const float* __restrict__ bu,
                                               const float* __restrict__ sv,
                                               float* __restrict__ out) {
  int lane = threadIdx.x & 63;
  float w[64];
#pragma unroll
  for (int k = 0; k < 64; ++k) w[k] = Wu[k * 64 + lane];
  float b = bu[lane];
  float w2v = sv[64 + lane];
  float c_all = sv[128];
  int wid = blockIdx.x * 4 + (threadIdx.x >> 6);
  for (int i = wid; i < NN; i += gridDim.x * 4) {
    float a = A[(size_t)i * 64 + lane];
    int beg = off[NN + NH + i], end = off[NN + NH + i + 1];
    float accm = 0.f;
    for (int j0 = beg; j0 < end; j0 += 64) {
      int m = end - j0; if (m > 64) m = 64;
      int aj = (lane < m) ? adj[j0 + lane] : 0;
      for (int k = 0; k < m; ++k) {
        int e = __shfl(aj, k);
        accm += fmaxf(a + B[(size_t)e * 64 + lane], 0.f);
      }
    }
    float hpre = accm * (0.5f / fmaxf((float)(end - beg), 1.0f)) + 0.5f * h[(size_t)i * 64 + lane];
    float a0 = b, a1 = 0.f;
#pragma unroll
    for (int k = 0; k < 64; k += 2) {
      a0 = fmaf(__shfl(hpre, k), w[k], a0);
      a1 = fmaf(__shfl(hpre, k + 1), w[k + 1], a1);
    }
    float part = fmaxf(a0 + a1, 0.f) * w2v;
    float di = dinv[i];
    int db = off[i], de = off[i + 1];
    float g = 0.f;
    for (int j = db + lane; j < de; j += 64) g += tp[adj[j]];
    float tot = waveReduceSum(part + g * di);
    if (lane == 0) out[i] = tot + tp[i] * di + c_all;
  }
}

// ---------------------------------------------------------------------------
extern "C" void kernel_launch(void* const* d_in, const int* in_sizes, int n_in,
                              void* d_out, int out_size, void* d_ws, size_t ws_size,
                              hipStream_t stream) {
  (void)in_sizes; (void)n_in; (void)out_size; (void)ws_size;
  const float* x       = (const float*)d_in[0];
  const int*   ei      = (const int*)d_in[1];
  const int*   hv      = (const int*)d_in[2];
  const int*   he      = (const int*)d_in[3];
  const float* conv1_W = (const float*)d_in[5];
  const float* conv1_b = (const float*)d_in[6];
  const float* conv2_W = (const float*)d_in[7];
  const float* conv2_b = (const float*)d_in[8];
  const float* lin_W   = (const float*)d_in[9];
  const float* lin_b   = (const float*)d_in[10];
  const float* W1      = (const float*)d_in[11];
  const float* b1      = (const float*)d_in[12];
  const float* W2      = (const float*)d_in[13];
  const float* b2      = (const float*)d_in[14];
  const float* Wu      = (const float*)d_in[15];
  const float* bu      = (const float*)d_in[16];
  const float* cls_W   = (const float*)d_in[17];
  const float* cls_b   = (const float*)d_in[18];
  const float* lp_W    = (const float*)d_in[19];
  const float* lp_b    = (const float*)d_in[20];
  const float* head_W  = (const float*)d_in[21];
  const float* head_b  = (const float*)d_in[22];
  const int* src = ei;
  const int* dst = ei + NE;
  float* out = (float*)d_out;

  // workspace (4B units). Aliasing: P = xw1' -> C.
  float* H     = (float*)d_ws;             // N*64
  float* P     = H + (size_t)NN * 64;      // N*64   xw1' then C
  float* Q     = P + (size_t)NN * 64;      // N*64   A
  float* XE    = Q + (size_t)NN * 64;      // NH*64  B
  float* DINV  = XE + (size_t)NH * 64;     // N
  float* TP    = DINV + NN;                // N   t' = t*dinv
  float* SV    = TP + NN;                  // 192
  int* GCNT    = (int*)(SV + 192);         // NBUK
  int* GBASE   = GCNT + NBUK;              // NBUK+1
  int* GCUR    = GBASE + NBUK + 1;         // NBUK
  int* OFF     = GCUR + NBUK;              // NS+1
  int* ADJ     = OFF + NS + 1;             // TOT
  // total ~95 MiB

  hipMemsetAsync(GCNT, 0, NBUK * 4, stream);

  k_vecs<<<1, 64, 0, stream>>>(conv2_W, conv2_b, cls_W, cls_b, lp_W, lp_b, head_W, head_b, SV);

  // CSR build (LDS-binned counting sort)
  k_ccount<<<512, 256, 0, stream>>>(dst, he, hv, GCNT);
  k_cscan<<<1, 1024, 0, stream>>>(GCNT, GBASE, GCUR);
  k_phase1<<<NWG1, 1024, 0, stream>>>(src, dst, he, hv, GCUR, ADJ);
  k_phase2<<<NBUK, 256, 0, stream>>>(GBASE, ADJ, OFF);
  k_dinv<<<(NN + 255) / 256, 256, 0, stream>>>(OFF, DINV);

  // dense: xw1' = (x @ conv1_W) * dinv[row]; h = relu(x @ lin_W + lin_b)
  k_gemm<128, false, false, true><<<2048, 256, 0, stream>>>(x, conv1_W, nullptr, DINV, P, NN);
  k_gemm<128, true, true, false><<<2048, 256, 0, stream>>>(x, lin_W, lin_b, nullptr, H, NN);

  // GCN branch collapsed to t' (conv2 folded into k_final)
  k_gcn1_gather<<<NN / 4, 256, 0, stream>>>(OFF, ADJ, P, DINV, conv1_b, SV, TP);

  // hyper branch dense parts: A = h @ W2[:64] (Q), C = h @ W1 + b1 (P)
  k_gemm<64, false, false, false><<<2048, 256, 0, stream>>>(H, W2, nullptr, nullptr, Q, NN);
  k_gemm<64, true, false, false><<<2048, 256, 0, stream>>>(H, W1, b1, nullptr, P, NN);

  k_xe_gather<<<2048, 256, 0, stream>>>(OFF, ADJ, P, W2, b2, XE);

  k_final<<<2048, 256, 0, stream>>>(OFF, ADJ, Q, XE, H, TP, DINV, Wu, bu, SV, out);
}